// Round 10
// baseline (449.507 us; speedup 1.0000x reference)
//
#include <hip/hip_runtime.h>

#define NGRAPH 512
#define DF     96
#define DHID   10
#define NCHUNK 256      // edge chunks (prep/scatter blocks)
#define NBINS  4096     // (graph, src-range) bins: g*8 + r
#define NTHR   256

// bf16 round-to-nearest-even
static __device__ __forceinline__ unsigned short f2bf(float f) {
    unsigned int u = __float_as_uint(f);
    u = (u + 0x7fffu + ((u >> 16) & 1u)) >> 16;
    return (unsigned short)u;
}
static __device__ __forceinline__ float bf2f(unsigned short s) {
    return __uint_as_float(((unsigned int)s) << 16);
}
static __device__ __forceinline__ unsigned short f2h(float f) {
    _Float16 h = (_Float16)f;
    unsigned short u;
    __builtin_memcpy(&u, &h, 2);
    return u;
}
static __device__ __forceinline__ float h2f(unsigned short u) {
    _Float16 h;
    __builtin_memcpy(&h, &u, 2);
    return (float)h;
}

// ---------------------------------------------------------------------------
// K1: x->bf16 conv + per-chunk bin histogram (bin-major scattered u16 stores)
//     + bin16 cache + zero done[] flags for this launch.
// ---------------------------------------------------------------------------
__global__ __launch_bounds__(NTHR) void prep_kernel(
    const int* __restrict__ edge_index,   // [2E]
    const int* __restrict__ batch,        // [N] sorted
    const float* __restrict__ x,          // [N*DF]
    int E, int N, int echunk, unsigned int M,
    unsigned short* __restrict__ hist,    // [NBINS*NCHUNK] bin-major
    unsigned short* __restrict__ bin16,   // [E]
    unsigned short* __restrict__ xb,      // [N*DF] bf16
    int* __restrict__ done)               // [NGRAPH]
{
    const int blk = blockIdx.x, t = threadIdx.x;

    if (blk == 0)
        for (int i = t; i < NGRAPH; i += NTHR) done[i] = 0;

    const int nf4 = N * DF / 4;
    for (int i = blk * NTHR + t; i < nf4; i += NCHUNK * NTHR) {
        const float4 v = ((const float4*)x)[i];
        ushort4 o;
        o.x = f2bf(v.x); o.y = f2bf(v.y); o.z = f2bf(v.z); o.w = f2bf(v.w);
        ((ushort4*)xb)[i] = o;
    }

    __shared__ int lh[NBINS];             // 16 KB
    for (int i = t; i < NBINS; i += NTHR) lh[i] = 0;
    __syncthreads();
    const int* __restrict__ src = edge_index;
    const int* __restrict__ dst = edge_index + E;
    const int lo = blk * echunk;
    const int hi = min(E, lo + echunk);
    for (int e = lo + t; e < hi; e += NTHR) {
        const int g = batch[dst[e]];
        const int r = (int)__umulhi((unsigned int)src[e], M);
        const int b = (g << 3) | r;
        bin16[e] = (unsigned short)b;
        atomicAdd(&lh[b], 1);
    }
    __syncthreads();
    for (int i = t; i < NBINS; i += NTHR)        // scattered u16 (stride 512B)
        hist[(size_t)i * NCHUNK + blk] = (unsigned short)lh[i];
}

// ---------------------------------------------------------------------------
// K2: per-bin prefix over chunks, fully coalesced. Block g owns bins 8g..8g+7;
//     32 threads/bin, 8 chunk-counts/thread (uint4 = 8 u16). Width-32 shuffle
//     scan. Outputs: baseT (bin-major rel. prefixes), binpre (g-local bin
//     prefix), blocksum (per-g total).
// ---------------------------------------------------------------------------
__global__ __launch_bounds__(NTHR) void scan_kernel(
    const unsigned short* __restrict__ hist,   // [NBINS*NCHUNK]
    unsigned short* __restrict__ baseT,        // [NBINS*NCHUNK]
    unsigned int* __restrict__ binpre,         // [NBINS]
    unsigned int* __restrict__ blocksum)       // [NGRAPH]
{
    __shared__ int btot[8];
    const int g = blockIdx.x, t = threadIdx.x;
    const int bloc = t >> 5, sub = t & 31;
    const int bin = (g << 3) | bloc;

    const uint4 raw = *(const uint4*)(hist + (size_t)bin * NCHUNK + sub * 8);
    int v[8];
    v[0] = raw.x & 0xffff; v[1] = raw.x >> 16;
    v[2] = raw.y & 0xffff; v[3] = raw.y >> 16;
    v[4] = raw.z & 0xffff; v[5] = raw.z >> 16;
    v[6] = raw.w & 0xffff; v[7] = raw.w >> 16;
    int pre[8], s = 0;
#pragma unroll
    for (int k = 0; k < 8; ++k) { pre[k] = s; s += v[k]; }
    int p = s;
#pragma unroll
    for (int d = 1; d < 32; d <<= 1) {
        const int u = __shfl_up(p, d, 32);
        if (sub >= d) p += u;
    }
    const int base = p - s;
    uint4 o;
    o.x = (unsigned int)((base + pre[0]) & 0xffff) | ((unsigned int)(base + pre[1]) << 16);
    o.y = (unsigned int)((base + pre[2]) & 0xffff) | ((unsigned int)(base + pre[3]) << 16);
    o.z = (unsigned int)((base + pre[4]) & 0xffff) | ((unsigned int)(base + pre[5]) << 16);
    o.w = (unsigned int)((base + pre[6]) & 0xffff) | ((unsigned int)(base + pre[7]) << 16);
    *(uint4*)(baseT + (size_t)bin * NCHUNK + sub * 8) = o;
    if (sub == 31) btot[bloc] = p;
    __syncthreads();
    if (t < 8) {
        int e = 0;
#pragma unroll
        for (int j = 0; j < 8; ++j) if (j < t) e += btot[j];
        binpre[(g << 3) | t] = (unsigned int)e;
        if (t == 7) blocksum[g] = (unsigned int)(e + btot[7]);
    }
}

// ---------------------------------------------------------------------------
// K3: scatter into bin-contiguous order. Preamble: 512-wide scan of blocksum
//     -> per-g starts; LDS cursors = start + binpre + per-chunk base.
//     Block 0 also writes soff[NBINS+1] for the aggregate kernel.
// ---------------------------------------------------------------------------
__global__ __launch_bounds__(NTHR) void scatter_kernel(
    const int* __restrict__ edge_index,
    const float* __restrict__ edge_attr,
    const unsigned short* __restrict__ bin16,
    const unsigned short* __restrict__ baseT,
    const unsigned int* __restrict__ binpre,
    const unsigned int* __restrict__ blocksum,
    int E, int echunk,
    int* __restrict__ soff,               // [NBINS+1] (written by block 0)
    unsigned int* __restrict__ ed)        // [E]: lo16 src, hi16 fp16(w)
{
    __shared__ int s512[NGRAPH];
    __shared__ int lcur[NBINS];
    __shared__ int wt[4];
    const int blk = blockIdx.x, t = threadIdx.x;
    const int lane = t & 63, wv = t >> 6;

    {   // exclusive scan of 512 per-g totals
        const int2 v = ((const int2*)blocksum)[t];
        const int s = v.x + v.y;
        int p = s;
#pragma unroll
        for (int d = 1; d < 64; d <<= 1) {
            const int u = __shfl_up(p, d, 64);
            if (lane >= d) p += u;
        }
        if (lane == 63) wt[wv] = p;
        __syncthreads();
        int add = 0;
#pragma unroll
        for (int i = 0; i < 4; ++i) if (i < wv) add += wt[i];
        const int excl = p + add - s;
        s512[2 * t]     = excl;
        s512[2 * t + 1] = excl + v.x;
    }
    __syncthreads();
    for (int i = t; i < NBINS; i += NTHR) {
        const int sv = s512[i >> 3] + (int)binpre[i];
        if (blk == 0) soff[i] = sv;
        lcur[i] = sv + (int)baseT[(size_t)i * NCHUNK + blk];
    }
    if (blk == 0 && t == 0) soff[NBINS] = E;
    __syncthreads();

    const int lo = blk * echunk;
    const int hi = min(E, lo + echunk);
    for (int e = lo + t; e < hi; e += NTHR) {
        const int b = bin16[e];
        const int p = atomicAdd(&lcur[b], 1);
        ed[p] = (unsigned int)(edge_index[e] & 0xffff)
              | ((unsigned int)f2h(edge_attr[e]) << 16);
    }
}

// ---------------------------------------------------------------------------
// K4: per-bin gather+accumulate -> partial; last block of each graph (done[g]
//     counter) reduces the 8 partials + mean + MLP head. blockIdx=bin=g*8+r
//     keeps each src-range's xb slice (1.2 MB) XCD-L2-local.
// ---------------------------------------------------------------------------
__global__ __launch_bounds__(NTHR) void aggregate_kernel(
    const unsigned int* __restrict__ ed,
    const int* __restrict__ soff,
    const unsigned short* __restrict__ xb,
    const int* __restrict__ batch,        // [N] sorted
    int N,
    const float* __restrict__ W1,
    const float* __restrict__ b1,
    const float* __restrict__ W2,
    const float* __restrict__ b2,
    float* __restrict__ partial,          // [NBINS*DF]
    int* __restrict__ done,               // [NGRAPH] zeroed by prep
    float* __restrict__ out)              // [NGRAPH]
{
    __shared__ float sh4[4][DF];
    __shared__ float sW1[DF * DHID];
    __shared__ float fin[DF];
    __shared__ int   scnt[2];
    __shared__ int   amLast;

    const int bin = blockIdx.x, t = threadIdx.x;
    const int g = bin >> 3;
    const int lane = t & 63, wv = t >> 6;
    const int start = soff[bin];
    const int end   = soff[bin + 1];
    const int eg = lane >> 3;
    const int fc = lane & 7;

    float acc[12];
#pragma unroll
    for (int i = 0; i < 12; ++i) acc[i] = 0.f;

    int e = start + wv * 8 + eg;
    unsigned int sw = (e < end) ? ed[e] : 0u;
    while (e < end) {
        const int en = e + 32;
        const unsigned int swn = (en < end) ? ed[en] : 0u;
        const float w = h2f((unsigned short)(sw >> 16));
        const ushort4* __restrict__ row =
            (const ushort4*)xb + (size_t)(sw & 0xffffu) * 24;
#pragma unroll
        for (int c = 0; c < 3; ++c) {
            const ushort4 vv = row[fc + c * 8];
            acc[c * 4 + 0] += w * bf2f(vv.x);
            acc[c * 4 + 1] += w * bf2f(vv.y);
            acc[c * 4 + 2] += w * bf2f(vv.z);
            acc[c * 4 + 3] += w * bf2f(vv.w);
        }
        e = en; sw = swn;
    }
#pragma unroll
    for (int m = 8; m <= 32; m <<= 1) {
#pragma unroll
        for (int i = 0; i < 12; ++i) acc[i] += __shfl_xor(acc[i], m, 64);
    }
    if (eg == 0) {
#pragma unroll
        for (int c = 0; c < 3; ++c)
#pragma unroll
            for (int k = 0; k < 4; ++k)
                sh4[wv][c * 32 + fc * 4 + k] = acc[c * 4 + k];
    }
    __syncthreads();
    if (t < DF)
        partial[(size_t)bin * DF + t] =
            sh4[0][t] + sh4[1][t] + sh4[2][t] + sh4[3][t];

    // ---- last-block-per-graph reduction + MLP ----
    __threadfence();                       // release partial[] device-wide
    if (t == 0) {
        const int old = __hip_atomic_fetch_add(&done[g], 1, __ATOMIC_ACQ_REL,
                                               __HIP_MEMORY_SCOPE_AGENT);
        amLast = (old == 7);
    }
    __syncthreads();
    if (!amLast) return;
    __threadfence();                       // acquire peers' partial[]

    if (t < 2) {
        const int key = g + t;
        int lo = 0, hi = N;
        while (lo < hi) {
            const int m = (lo + hi) >> 1;
            if (batch[m] < key) lo = m + 1; else hi = m;
        }
        scnt[t] = lo;
    }
    for (int i = t; i < DF * DHID; i += NTHR) sW1[i] = W1[i];
    __syncthreads();
    if (t < DF) {
        float s = 0.f;
#pragma unroll
        for (int r = 0; r < 8; ++r)
            s += partial[(size_t)((g << 3) | r) * DF + t];
        const int cnt = scnt[1] - scnt[0];
        fin[t] = fmaxf(s / fmaxf((float)cnt, 1.f), 0.f);
    }
    __syncthreads();
    if (t < 16) {
        float v = 0.f;
        if (t < DHID) {
            float h = b1[t];
            for (int f = 0; f < DF; ++f) h += fin[f] * sW1[f * DHID + t];
            v = fmaxf(h, 0.f) * W2[t];
        }
#pragma unroll
        for (int m = 1; m < 16; m <<= 1) v += __shfl_xor(v, m, 16);
        if (t == 0) out[g] = v + b2[0];
    }
}

// ---------------------------------------------------------------------------
extern "C" void kernel_launch(void* const* d_in, const int* in_sizes, int n_in,
                              void* d_out, int out_size, void* d_ws, size_t ws_size,
                              hipStream_t stream) {
    const float* x          = (const float*)d_in[0];
    const int*   edge_index = (const int*)  d_in[1];
    const float* edge_attr  = (const float*)d_in[2];
    const int*   batch      = (const int*)  d_in[3];
    const float* W1         = (const float*)d_in[4];
    const float* b1         = (const float*)d_in[5];
    const float* W2         = (const float*)d_in[6];
    const float* b2         = (const float*)d_in[7];

    const int E = in_sizes[1] / 2;   // 800000
    const int N = in_sizes[3];       // 50000 (< 65536: src fits u16)
    const int echunk = (E + NCHUNK - 1) / NCHUNK;
    const unsigned int RDIV = (unsigned int)((N + 7) / 8);
    const unsigned int M = (unsigned int)((0x100000000ULL + RDIV - 1) / RDIV);

    char* ws = (char*)d_ws;
    unsigned int*   ed    = (unsigned int*)ws;                       // 4E
    unsigned short* bin16 = (unsigned short*)(ws + (size_t)4 * E);   // 2E
    unsigned short* xb    = (unsigned short*)(ws + (size_t)6 * E);   // 2*N*DF
    char* tail = ws + (size_t)6 * E + (size_t)2 * N * DF;
    tail = (char*)(((size_t)tail + 255) & ~(size_t)255);
    unsigned short* hist     = (unsigned short*)tail;                  // 2 MB
    unsigned short* baseT    = hist + (size_t)NBINS * NCHUNK;          // 2 MB
    unsigned int*   binpre   = (unsigned int*)(baseT + (size_t)NBINS * NCHUNK);
    unsigned int*   blocksum = binpre + NBINS;
    int*            soff     = (int*)(blocksum + NGRAPH);              // NBINS+1
    int*            done     = soff + NBINS + 4;                       // NGRAPH
    float*          partial  = (float*)(done + NGRAPH);                // NBINS*DF

    prep_kernel<<<NCHUNK, NTHR, 0, stream>>>(edge_index, batch, x, E, N,
                                             echunk, M, hist, bin16, xb, done);
    scan_kernel<<<NGRAPH, NTHR, 0, stream>>>(hist, baseT, binpre, blocksum);
    scatter_kernel<<<NCHUNK, NTHR, 0, stream>>>(edge_index, edge_attr, bin16,
                                                baseT, binpre, blocksum,
                                                E, echunk, soff, ed);
    aggregate_kernel<<<NBINS, NTHR, 0, stream>>>(ed, soff, xb, batch, N,
                                                 W1, b1, W2, b2,
                                                 partial, done, (float*)d_out);
}

// Round 11
// 70.823 us; speedup vs baseline: 6.3469x; 6.3469x over previous
//
#include <hip/hip_runtime.h>

#define NGRAPH 512
#define DF     96
#define DHID   10
#define NCHUNK 256      // edge chunks (prep/scatter blocks)
#define NBINS  4096     // (graph, src-range) bins: g*8 + r
#define NTHR   256

// bf16 round-to-nearest-even
static __device__ __forceinline__ unsigned short f2bf(float f) {
    unsigned int u = __float_as_uint(f);
    u = (u + 0x7fffu + ((u >> 16) & 1u)) >> 16;
    return (unsigned short)u;
}
static __device__ __forceinline__ float bf2f(unsigned short s) {
    return __uint_as_float(((unsigned int)s) << 16);
}
static __device__ __forceinline__ unsigned short f2h(float f) {
    _Float16 h = (_Float16)f;
    unsigned short u;
    __builtin_memcpy(&u, &h, 2);
    return u;
}
static __device__ __forceinline__ float h2f(unsigned short u) {
    _Float16 h;
    __builtin_memcpy(&h, &u, 2);
    return (float)h;
}

// ---------------------------------------------------------------------------
// K1: x->bf16 conv + per-chunk bin histogram (bin-major u16 stores) + bin16.
// ---------------------------------------------------------------------------
__global__ __launch_bounds__(NTHR) void prep_kernel(
    const int* __restrict__ edge_index,   // [2E]
    const int* __restrict__ batch,        // [N] sorted
    const float* __restrict__ x,          // [N*DF]
    int E, int N, int echunk, unsigned int M,
    unsigned short* __restrict__ hist,    // [NBINS*NCHUNK] bin-major
    unsigned short* __restrict__ bin16,   // [E]
    unsigned short* __restrict__ xb)      // [N*DF] bf16
{
    const int blk = blockIdx.x, t = threadIdx.x;

    const int nf4 = N * DF / 4;
    for (int i = blk * NTHR + t; i < nf4; i += NCHUNK * NTHR) {
        const float4 v = ((const float4*)x)[i];
        ushort4 o;
        o.x = f2bf(v.x); o.y = f2bf(v.y); o.z = f2bf(v.z); o.w = f2bf(v.w);
        ((ushort4*)xb)[i] = o;
    }

    __shared__ int lh[NBINS];             // 16 KB
    for (int i = t; i < NBINS; i += NTHR) lh[i] = 0;
    __syncthreads();
    const int* __restrict__ src = edge_index;
    const int* __restrict__ dst = edge_index + E;
    const int lo = blk * echunk;
    const int hi = min(E, lo + echunk);
    for (int e = lo + t; e < hi; e += NTHR) {
        const int g = batch[dst[e]];
        const int r = (int)__umulhi((unsigned int)src[e], M);
        const int b = (g << 3) | r;
        bin16[e] = (unsigned short)b;
        atomicAdd(&lh[b], 1);
    }
    __syncthreads();
    for (int i = t; i < NBINS; i += NTHR)        // u16, stride 512B (L2-absorbed)
        hist[(size_t)i * NCHUNK + blk] = (unsigned short)lh[i];
}

// ---------------------------------------------------------------------------
// K2: per-bin prefix over chunks, fully coalesced. Block g owns bins 8g..8g+7;
//     32 threads/bin, 8 chunk-counts/thread (uint4). Width-32 shuffle scan.
// ---------------------------------------------------------------------------
__global__ __launch_bounds__(NTHR) void scan_kernel(
    const unsigned short* __restrict__ hist,   // [NBINS*NCHUNK]
    unsigned short* __restrict__ baseT,        // [NBINS*NCHUNK]
    unsigned int* __restrict__ binpre,         // [NBINS]
    unsigned int* __restrict__ blocksum)       // [NGRAPH]
{
    __shared__ int btot[8];
    const int g = blockIdx.x, t = threadIdx.x;
    const int bloc = t >> 5, sub = t & 31;
    const int bin = (g << 3) | bloc;

    const uint4 raw = *(const uint4*)(hist + (size_t)bin * NCHUNK + sub * 8);
    int v[8];
    v[0] = raw.x & 0xffff; v[1] = raw.x >> 16;
    v[2] = raw.y & 0xffff; v[3] = raw.y >> 16;
    v[4] = raw.z & 0xffff; v[5] = raw.z >> 16;
    v[6] = raw.w & 0xffff; v[7] = raw.w >> 16;
    int pre[8], s = 0;
#pragma unroll
    for (int k = 0; k < 8; ++k) { pre[k] = s; s += v[k]; }
    int p = s;
#pragma unroll
    for (int d = 1; d < 32; d <<= 1) {
        const int u = __shfl_up(p, d, 32);
        if (sub >= d) p += u;
    }
    const int base = p - s;
    uint4 o;
    o.x = (unsigned int)((base + pre[0]) & 0xffff) | ((unsigned int)(base + pre[1]) << 16);
    o.y = (unsigned int)((base + pre[2]) & 0xffff) | ((unsigned int)(base + pre[3]) << 16);
    o.z = (unsigned int)((base + pre[4]) & 0xffff) | ((unsigned int)(base + pre[5]) << 16);
    o.w = (unsigned int)((base + pre[6]) & 0xffff) | ((unsigned int)(base + pre[7]) << 16);
    *(uint4*)(baseT + (size_t)bin * NCHUNK + sub * 8) = o;
    if (sub == 31) btot[bloc] = p;
    __syncthreads();
    if (t < 8) {
        int e = 0;
#pragma unroll
        for (int j = 0; j < 8; ++j) if (j < t) e += btot[j];
        binpre[(g << 3) | t] = (unsigned int)e;
        if (t == 7) blocksum[g] = (unsigned int)(e + btot[7]);
    }
}

// ---------------------------------------------------------------------------
// K3: scatter into bin-contiguous order. Preamble: 512-wide scan of blocksum;
//     LDS cursors = start + binpre + per-chunk base. Block 0 writes soff[].
// ---------------------------------------------------------------------------
__global__ __launch_bounds__(NTHR) void scatter_kernel(
    const int* __restrict__ edge_index,
    const float* __restrict__ edge_attr,
    const unsigned short* __restrict__ bin16,
    const unsigned short* __restrict__ baseT,
    const unsigned int* __restrict__ binpre,
    const unsigned int* __restrict__ blocksum,
    int E, int echunk,
    int* __restrict__ soff,               // [NBINS+1] (written by block 0)
    unsigned int* __restrict__ ed)        // [E]: lo16 src, hi16 fp16(w)
{
    __shared__ int s512[NGRAPH];
    __shared__ int lcur[NBINS];
    __shared__ int wt[4];
    const int blk = blockIdx.x, t = threadIdx.x;
    const int lane = t & 63, wv = t >> 6;

    {   // exclusive scan of 512 per-g totals
        const int2 v = ((const int2*)blocksum)[t];
        const int s = v.x + v.y;
        int p = s;
#pragma unroll
        for (int d = 1; d < 64; d <<= 1) {
            const int u = __shfl_up(p, d, 64);
            if (lane >= d) p += u;
        }
        if (lane == 63) wt[wv] = p;
        __syncthreads();
        int add = 0;
#pragma unroll
        for (int i = 0; i < 4; ++i) if (i < wv) add += wt[i];
        const int excl = p + add - s;
        s512[2 * t]     = excl;
        s512[2 * t + 1] = excl + v.x;
    }
    __syncthreads();
    for (int i = t; i < NBINS; i += NTHR) {
        const int sv = s512[i >> 3] + (int)binpre[i];
        if (blk == 0) soff[i] = sv;
        lcur[i] = sv + (int)baseT[(size_t)i * NCHUNK + blk];
    }
    if (blk == 0 && t == 0) soff[NBINS] = E;
    __syncthreads();

    const int lo = blk * echunk;
    const int hi = min(E, lo + echunk);
    for (int e = lo + t; e < hi; e += NTHR) {
        const int b = bin16[e];
        const int p = atomicAdd(&lcur[b], 1);
        ed[p] = (unsigned int)(edge_index[e] & 0xffff)
              | ((unsigned int)f2h(edge_attr[e]) << 16);
    }
}

// ---------------------------------------------------------------------------
// K4: per-bin gather + accumulate -> partial[bin][96]. blockIdx=bin=g*8+r:
//     consecutive blocks round-robin XCDs -> slice r's xb (1.2 MB) stays
//     XCD-L2-local. NO fences — finish is a separate stream-ordered dispatch.
// ---------------------------------------------------------------------------
__global__ __launch_bounds__(NTHR) void aggregate_kernel(
    const unsigned int* __restrict__ ed,
    const int* __restrict__ soff,
    const unsigned short* __restrict__ xb,
    float* __restrict__ partial)          // [NBINS*DF]
{
    __shared__ float sh4[4][DF];
    const int bin = blockIdx.x, t = threadIdx.x;
    const int lane = t & 63, wv = t >> 6;
    const int start = soff[bin];
    const int end   = soff[bin + 1];
    const int eg = lane >> 3;
    const int fc = lane & 7;

    float acc[12];
#pragma unroll
    for (int i = 0; i < 12; ++i) acc[i] = 0.f;

    int e = start + wv * 8 + eg;
    unsigned int sw = (e < end) ? ed[e] : 0u;
    while (e < end) {
        const int en = e + 32;
        const unsigned int swn = (en < end) ? ed[en] : 0u;
        const float w = h2f((unsigned short)(sw >> 16));
        const ushort4* __restrict__ row =
            (const ushort4*)xb + (size_t)(sw & 0xffffu) * 24;
#pragma unroll
        for (int c = 0; c < 3; ++c) {
            const ushort4 vv = row[fc + c * 8];
            acc[c * 4 + 0] += w * bf2f(vv.x);
            acc[c * 4 + 1] += w * bf2f(vv.y);
            acc[c * 4 + 2] += w * bf2f(vv.z);
            acc[c * 4 + 3] += w * bf2f(vv.w);
        }
        e = en; sw = swn;
    }
#pragma unroll
    for (int m = 8; m <= 32; m <<= 1) {
#pragma unroll
        for (int i = 0; i < 12; ++i) acc[i] += __shfl_xor(acc[i], m, 64);
    }
    if (eg == 0) {
#pragma unroll
        for (int c = 0; c < 3; ++c)
#pragma unroll
            for (int k = 0; k < 4; ++k)
                sh4[wv][c * 32 + fc * 4 + k] = acc[c * 4 + k];
    }
    __syncthreads();
    if (t < DF)
        partial[(size_t)bin * DF + t] =
            sh4[0][t] + sh4[1][t] + sh4[2][t] + sh4[3][t];
}

// ---------------------------------------------------------------------------
// K5: reduce 8 range-partials + mean (bsearch counts) + MLP head.
// ---------------------------------------------------------------------------
__global__ __launch_bounds__(128) void finish_kernel(
    const float* __restrict__ partial,    // [NBINS*DF]
    const int* __restrict__ batch,        // [N] sorted
    int N,
    const float* __restrict__ W1,
    const float* __restrict__ b1,
    const float* __restrict__ W2,
    const float* __restrict__ b2,
    float* __restrict__ out)
{
    __shared__ float sW1[DF * DHID];
    __shared__ float fin[DF];
    __shared__ int   scnt[2];
    const int g = blockIdx.x, t = threadIdx.x;

    if (t < 2) {
        const int key = g + t;
        int lo = 0, hi = N;
        while (lo < hi) {
            const int m = (lo + hi) >> 1;
            if (batch[m] < key) lo = m + 1; else hi = m;
        }
        scnt[t] = lo;
    }
    for (int i = t; i < DF * DHID; i += 128) sW1[i] = W1[i];
    __syncthreads();

    if (t < DF) {
        float s = 0.f;
#pragma unroll
        for (int r = 0; r < 8; ++r)
            s += partial[(size_t)((g << 3) | r) * DF + t];
        const int cnt = scnt[1] - scnt[0];
        fin[t] = fmaxf(s / fmaxf((float)cnt, 1.f), 0.f);
    }
    __syncthreads();
    if (t < 16) {
        float v = 0.f;
        if (t < DHID) {
            float h = b1[t];
            for (int f = 0; f < DF; ++f) h += fin[f] * sW1[f * DHID + t];
            v = fmaxf(h, 0.f) * W2[t];
        }
#pragma unroll
        for (int m = 1; m < 16; m <<= 1) v += __shfl_xor(v, m, 16);
        if (t == 0) out[g] = v + b2[0];
    }
}

// ---------------------------------------------------------------------------
extern "C" void kernel_launch(void* const* d_in, const int* in_sizes, int n_in,
                              void* d_out, int out_size, void* d_ws, size_t ws_size,
                              hipStream_t stream) {
    const float* x          = (const float*)d_in[0];
    const int*   edge_index = (const int*)  d_in[1];
    const float* edge_attr  = (const float*)d_in[2];
    const int*   batch      = (const int*)  d_in[3];
    const float* W1         = (const float*)d_in[4];
    const float* b1         = (const float*)d_in[5];
    const float* W2         = (const float*)d_in[6];
    const float* b2         = (const float*)d_in[7];

    const int E = in_sizes[1] / 2;   // 800000
    const int N = in_sizes[3];       // 50000 (< 65536: src fits u16)
    const int echunk = (E + NCHUNK - 1) / NCHUNK;
    const unsigned int RDIV = (unsigned int)((N + 7) / 8);
    const unsigned int M = (unsigned int)((0x100000000ULL + RDIV - 1) / RDIV);

    char* ws = (char*)d_ws;
    unsigned int*   ed    = (unsigned int*)ws;                       // 4E
    unsigned short* bin16 = (unsigned short*)(ws + (size_t)4 * E);   // 2E
    unsigned short* xb    = (unsigned short*)(ws + (size_t)6 * E);   // 2*N*DF
    char* tail = ws + (size_t)6 * E + (size_t)2 * N * DF;
    tail = (char*)(((size_t)tail + 255) & ~(size_t)255);
    unsigned short* hist     = (unsigned short*)tail;                  // 2 MB
    unsigned short* baseT    = hist + (size_t)NBINS * NCHUNK;          // 2 MB
    unsigned int*   binpre   = (unsigned int*)(baseT + (size_t)NBINS * NCHUNK);
    unsigned int*   blocksum = binpre + NBINS;
    int*            soff     = (int*)(blocksum + NGRAPH);              // NBINS+1
    float*          partial  = (float*)(soff + NBINS + 4);             // NBINS*DF

    prep_kernel<<<NCHUNK, NTHR, 0, stream>>>(edge_index, batch, x, E, N,
                                             echunk, M, hist, bin16, xb);
    scan_kernel<<<NGRAPH, NTHR, 0, stream>>>(hist, baseT, binpre, blocksum);
    scatter_kernel<<<NCHUNK, NTHR, 0, stream>>>(edge_index, edge_attr, bin16,
                                                baseT, binpre, blocksum,
                                                E, echunk, soff, ed);
    aggregate_kernel<<<NBINS, NTHR, 0, stream>>>(ed, soff, xb, partial);
    finish_kernel<<<NGRAPH, 128, 0, stream>>>(partial, batch, N,
                                              W1, b1, W2, b2, (float*)d_out);
}

// Round 12
// 67.940 us; speedup vs baseline: 6.6162x; 1.0424x over previous
//
#include <hip/hip_runtime.h>

#define NGRAPH 512
#define DF     96
#define DHID   10
#define NCHUNK 256      // edge chunks (prep/scatter blocks)
#define NBINS  4096     // (graph, src-range) bins: g*8 + r
#define NTHR   256

// bf16 round-to-nearest-even
static __device__ __forceinline__ unsigned short f2bf(float f) {
    unsigned int u = __float_as_uint(f);
    u = (u + 0x7fffu + ((u >> 16) & 1u)) >> 16;
    return (unsigned short)u;
}
static __device__ __forceinline__ float bf2f(unsigned short s) {
    return __uint_as_float(((unsigned int)s) << 16);
}
static __device__ __forceinline__ unsigned short f2h(float f) {
    _Float16 h = (_Float16)f;
    unsigned short u;
    __builtin_memcpy(&u, &h, 2);
    return u;
}
static __device__ __forceinline__ float h2f(unsigned short u) {
    _Float16 h;
    __builtin_memcpy(&h, &u, 2);
    return (float)h;
}

// ---------------------------------------------------------------------------
// K1: x->bf16 conv + per-chunk bin histogram (CHUNK-major: coalesced u16
//     stores) + bin16 cache.
// ---------------------------------------------------------------------------
__global__ __launch_bounds__(NTHR) void prep_kernel(
    const int* __restrict__ edge_index,   // [2E]
    const int* __restrict__ batch,        // [N] sorted
    const float* __restrict__ x,          // [N*DF]
    int E, int N, int echunk, unsigned int M,
    unsigned short* __restrict__ hist,    // [NCHUNK*NBINS] chunk-major
    unsigned short* __restrict__ bin16,   // [E]
    unsigned short* __restrict__ xb)      // [N*DF] bf16
{
    const int blk = blockIdx.x, t = threadIdx.x;

    const int nf4 = N * DF / 4;
    for (int i = blk * NTHR + t; i < nf4; i += NCHUNK * NTHR) {
        const float4 v = ((const float4*)x)[i];
        ushort4 o;
        o.x = f2bf(v.x); o.y = f2bf(v.y); o.z = f2bf(v.z); o.w = f2bf(v.w);
        ((ushort4*)xb)[i] = o;
    }

    __shared__ int lh[NBINS];             // 16 KB
    for (int i = t; i < NBINS; i += NTHR) lh[i] = 0;
    __syncthreads();
    const int* __restrict__ src = edge_index;
    const int* __restrict__ dst = edge_index + E;
    const int lo = blk * echunk;
    const int hi = min(E, lo + echunk);
    for (int e = lo + t; e < hi; e += NTHR) {
        const int g = batch[dst[e]];
        const int r = (int)__umulhi((unsigned int)src[e], M);
        const int b = (g << 3) | r;
        bin16[e] = (unsigned short)b;
        atomicAdd(&lh[b], 1);
    }
    __syncthreads();
    for (int i = t; i < NBINS; i += NTHR)        // coalesced u16 row write
        hist[(size_t)blk * NBINS + i] = (unsigned short)lh[i];
}

// ---------------------------------------------------------------------------
// K2: per-bin prefix over chunks with CHUNK-major layout. Block g owns bins
//     8g..8g+7; thread t holds the 8 bins' counts at chunk t (one uint4).
//     8 block-wide shuffle scans over the chunk axis; uint4 store back.
// ---------------------------------------------------------------------------
__global__ __launch_bounds__(NTHR) void scan_kernel(
    const unsigned short* __restrict__ hist,   // [NCHUNK*NBINS]
    unsigned short* __restrict__ baseT,        // [NCHUNK*NBINS]
    unsigned int* __restrict__ binpre,         // [NBINS]
    unsigned int* __restrict__ blocksum)       // [NGRAPH]
{
    __shared__ int wt[4];
    __shared__ int btot[8];
    const int g = blockIdx.x, t = threadIdx.x;
    const int lane = t & 63, wv = t >> 6;

    const uint4 raw = *(const uint4*)(hist + (size_t)t * NBINS + 8 * g);
    int v[8];
    v[0] = raw.x & 0xffff; v[1] = raw.x >> 16;
    v[2] = raw.y & 0xffff; v[3] = raw.y >> 16;
    v[4] = raw.z & 0xffff; v[5] = raw.z >> 16;
    v[6] = raw.w & 0xffff; v[7] = raw.w >> 16;

    int pre[8];
#pragma unroll
    for (int k = 0; k < 8; ++k) {
        int p = v[k];
#pragma unroll
        for (int d = 1; d < 64; d <<= 1) {          // wave inclusive scan
            const int u = __shfl_up(p, d, 64);
            if (lane >= d) p += u;
        }
        if (lane == 63) wt[wv] = p;
        __syncthreads();
        int add = 0;
#pragma unroll
        for (int i = 0; i < 4; ++i) if (i < wv) add += wt[i];
        pre[k] = p + add - v[k];                    // block-exclusive
        if (t == NTHR - 1) btot[k] = p + add;       // block total
        __syncthreads();                            // wt reuse guard
    }

    uint4 o;
    o.x = (unsigned int)(pre[0] & 0xffff) | ((unsigned int)(pre[1] & 0xffff) << 16);
    o.y = (unsigned int)(pre[2] & 0xffff) | ((unsigned int)(pre[3] & 0xffff) << 16);
    o.z = (unsigned int)(pre[4] & 0xffff) | ((unsigned int)(pre[5] & 0xffff) << 16);
    o.w = (unsigned int)(pre[6] & 0xffff) | ((unsigned int)(pre[7] & 0xffff) << 16);
    *(uint4*)(baseT + (size_t)t * NBINS + 8 * g) = o;

    if (t < 8) {
        int e = 0;
#pragma unroll
        for (int j = 0; j < 8; ++j) if (j < t) e += btot[j];
        binpre[(g << 3) | t] = (unsigned int)e;
        if (t == 7) blocksum[g] = (unsigned int)(e + btot[7]);
    }
}

// ---------------------------------------------------------------------------
// K3: scatter into bin-contiguous order. Preamble: 512-wide scan of blocksum;
//     LDS cursors = start + binpre + per-chunk base (chunk-major, coalesced).
//     Block 0 writes soff[].
// ---------------------------------------------------------------------------
__global__ __launch_bounds__(NTHR) void scatter_kernel(
    const int* __restrict__ edge_index,
    const float* __restrict__ edge_attr,
    const unsigned short* __restrict__ bin16,
    const unsigned short* __restrict__ baseT,
    const unsigned int* __restrict__ binpre,
    const unsigned int* __restrict__ blocksum,
    int E, int echunk,
    int* __restrict__ soff,               // [NBINS+1] (written by block 0)
    unsigned int* __restrict__ ed)        // [E]: lo16 src, hi16 fp16(w)
{
    __shared__ int s512[NGRAPH];
    __shared__ int lcur[NBINS];
    __shared__ int wt[4];
    const int blk = blockIdx.x, t = threadIdx.x;
    const int lane = t & 63, wv = t >> 6;

    {   // exclusive scan of 512 per-g totals
        const int2 v = ((const int2*)blocksum)[t];
        const int s = v.x + v.y;
        int p = s;
#pragma unroll
        for (int d = 1; d < 64; d <<= 1) {
            const int u = __shfl_up(p, d, 64);
            if (lane >= d) p += u;
        }
        if (lane == 63) wt[wv] = p;
        __syncthreads();
        int add = 0;
#pragma unroll
        for (int i = 0; i < 4; ++i) if (i < wv) add += wt[i];
        const int excl = p + add - s;
        s512[2 * t]     = excl;
        s512[2 * t + 1] = excl + v.x;
    }
    __syncthreads();
    for (int i = t; i < NBINS; i += NTHR) {
        const int sv = s512[i >> 3] + (int)binpre[i];
        if (blk == 0) soff[i] = sv;
        lcur[i] = sv + (int)baseT[(size_t)blk * NBINS + i];   // coalesced
    }
    if (blk == 0 && t == 0) soff[NBINS] = E;
    __syncthreads();

    const int lo = blk * echunk;
    const int hi = min(E, lo + echunk);
    for (int e = lo + t; e < hi; e += NTHR) {
        const int b = bin16[e];
        const int p = atomicAdd(&lcur[b], 1);
        ed[p] = (unsigned int)(edge_index[e] & 0xffff)
              | ((unsigned int)f2h(edge_attr[e]) << 16);
    }
}

// ---------------------------------------------------------------------------
// K4: per-bin gather + accumulate -> partial[bin][96]. blockIdx=bin=g*8+r:
//     consecutive blocks round-robin XCDs -> slice r's xb (1.2 MB) stays
//     XCD-L2-local. NO fences.
// ---------------------------------------------------------------------------
__global__ __launch_bounds__(NTHR) void aggregate_kernel(
    const unsigned int* __restrict__ ed,
    const int* __restrict__ soff,
    const unsigned short* __restrict__ xb,
    float* __restrict__ partial)          // [NBINS*DF]
{
    __shared__ float sh4[4][DF];
    const int bin = blockIdx.x, t = threadIdx.x;
    const int lane = t & 63, wv = t >> 6;
    const int start = soff[bin];
    const int end   = soff[bin + 1];
    const int eg = lane >> 3;
    const int fc = lane & 7;

    float acc[12];
#pragma unroll
    for (int i = 0; i < 12; ++i) acc[i] = 0.f;

    int e = start + wv * 8 + eg;
    unsigned int sw = (e < end) ? ed[e] : 0u;
    while (e < end) {
        const int en = e + 32;
        const unsigned int swn = (en < end) ? ed[en] : 0u;
        const float w = h2f((unsigned short)(sw >> 16));
        const ushort4* __restrict__ row =
            (const ushort4*)xb + (size_t)(sw & 0xffffu) * 24;
#pragma unroll
        for (int c = 0; c < 3; ++c) {
            const ushort4 vv = row[fc + c * 8];
            acc[c * 4 + 0] += w * bf2f(vv.x);
            acc[c * 4 + 1] += w * bf2f(vv.y);
            acc[c * 4 + 2] += w * bf2f(vv.z);
            acc[c * 4 + 3] += w * bf2f(vv.w);
        }
        e = en; sw = swn;
    }
#pragma unroll
    for (int m = 8; m <= 32; m <<= 1) {
#pragma unroll
        for (int i = 0; i < 12; ++i) acc[i] += __shfl_xor(acc[i], m, 64);
    }
    if (eg == 0) {
#pragma unroll
        for (int c = 0; c < 3; ++c)
#pragma unroll
            for (int k = 0; k < 4; ++k)
                sh4[wv][c * 32 + fc * 4 + k] = acc[c * 4 + k];
    }
    __syncthreads();
    if (t < DF)
        partial[(size_t)bin * DF + t] =
            sh4[0][t] + sh4[1][t] + sh4[2][t] + sh4[3][t];
}

// ---------------------------------------------------------------------------
// K5: reduce 8 range-partials + mean (bsearch counts) + MLP head.
// ---------------------------------------------------------------------------
__global__ __launch_bounds__(128) void finish_kernel(
    const float* __restrict__ partial,    // [NBINS*DF]
    const int* __restrict__ batch,        // [N] sorted
    int N,
    const float* __restrict__ W1,
    const float* __restrict__ b1,
    const float* __restrict__ W2,
    const float* __restrict__ b2,
    float* __restrict__ out)
{
    __shared__ float sW1[DF * DHID];
    __shared__ float fin[DF];
    __shared__ int   scnt[2];
    const int g = blockIdx.x, t = threadIdx.x;

    if (t < 2) {
        const int key = g + t;
        int lo = 0, hi = N;
        while (lo < hi) {
            const int m = (lo + hi) >> 1;
            if (batch[m] < key) lo = m + 1; else hi = m;
        }
        scnt[t] = lo;
    }
    for (int i = t; i < DF * DHID; i += 128) sW1[i] = W1[i];
    __syncthreads();

    if (t < DF) {
        float s = 0.f;
#pragma unroll
        for (int r = 0; r < 8; ++r)
            s += partial[(size_t)((g << 3) | r) * DF + t];
        const int cnt = scnt[1] - scnt[0];
        fin[t] = fmaxf(s / fmaxf((float)cnt, 1.f), 0.f);
    }
    __syncthreads();
    if (t < 16) {
        float v = 0.f;
        if (t < DHID) {
            float h = b1[t];
            for (int f = 0; f < DF; ++f) h += fin[f] * sW1[f * DHID + t];
            v = fmaxf(h, 0.f) * W2[t];
        }
#pragma unroll
        for (int m = 1; m < 16; m <<= 1) v += __shfl_xor(v, m, 16);
        if (t == 0) out[g] = v + b2[0];
    }
}

// ---------------------------------------------------------------------------
extern "C" void kernel_launch(void* const* d_in, const int* in_sizes, int n_in,
                              void* d_out, int out_size, void* d_ws, size_t ws_size,
                              hipStream_t stream) {
    const float* x          = (const float*)d_in[0];
    const int*   edge_index = (const int*)  d_in[1];
    const float* edge_attr  = (const float*)d_in[2];
    const int*   batch      = (const int*)  d_in[3];
    const float* W1         = (const float*)d_in[4];
    const float* b1         = (const float*)d_in[5];
    const float* W2         = (const float*)d_in[6];
    const float* b2         = (const float*)d_in[7];

    const int E = in_sizes[1] / 2;   // 800000
    const int N = in_sizes[3];       // 50000 (< 65536: src fits u16)
    const int echunk = (E + NCHUNK - 1) / NCHUNK;
    const unsigned int RDIV = (unsigned int)((N + 7) / 8);
    const unsigned int M = (unsigned int)((0x100000000ULL + RDIV - 1) / RDIV);

    char* ws = (char*)d_ws;
    unsigned int*   ed    = (unsigned int*)ws;                       // 4E
    unsigned short* bin16 = (unsigned short*)(ws + (size_t)4 * E);   // 2E
    unsigned short* xb    = (unsigned short*)(ws + (size_t)6 * E);   // 2*N*DF
    char* tail = ws + (size_t)6 * E + (size_t)2 * N * DF;
    tail = (char*)(((size_t)tail + 255) & ~(size_t)255);
    unsigned short* hist     = (unsigned short*)tail;                  // 2 MB
    unsigned short* baseT    = hist + (size_t)NCHUNK * NBINS;          // 2 MB
    unsigned int*   binpre   = (unsigned int*)(baseT + (size_t)NCHUNK * NBINS);
    unsigned int*   blocksum = binpre + NBINS;
    int*            soff     = (int*)(blocksum + NGRAPH);              // NBINS+1
    float*          partial  = (float*)(soff + NBINS + 4);             // NBINS*DF

    prep_kernel<<<NCHUNK, NTHR, 0, stream>>>(edge_index, batch, x, E, N,
                                             echunk, M, hist, bin16, xb);
    scan_kernel<<<NGRAPH, NTHR, 0, stream>>>(hist, baseT, binpre, blocksum);
    scatter_kernel<<<NCHUNK, NTHR, 0, stream>>>(edge_index, edge_attr, bin16,
                                                baseT, binpre, blocksum,
                                                E, echunk, soff, ed);
    aggregate_kernel<<<NBINS, NTHR, 0, stream>>>(ed, soff, xb, partial);
    finish_kernel<<<NGRAPH, 128, 0, stream>>>(partial, batch, N,
                                              W1, b1, W2, b2, (float*)d_out);
}

// Round 13
// 60.344 us; speedup vs baseline: 7.4490x; 1.1259x over previous
//
#include <hip/hip_runtime.h>

#define NGRAPH 512
#define DF     96
#define DHID   10
#define NCHUNK 256      // edge chunks (prep/scatter blocks)
#define NBINS  4096     // (graph, src-range) bins: g*8 + r
#define NTHR   256      // scan / aggregate / finish block size
#define HTHR   1024     // prep / scatter block size (16 waves/CU)

// bf16 round-to-nearest-even
static __device__ __forceinline__ unsigned short f2bf(float f) {
    unsigned int u = __float_as_uint(f);
    u = (u + 0x7fffu + ((u >> 16) & 1u)) >> 16;
    return (unsigned short)u;
}
static __device__ __forceinline__ float bf2f(unsigned short s) {
    return __uint_as_float(((unsigned int)s) << 16);
}
static __device__ __forceinline__ unsigned short f2h(float f) {
    _Float16 h = (_Float16)f;
    unsigned short u;
    __builtin_memcpy(&u, &h, 2);
    return u;
}
static __device__ __forceinline__ float h2f(unsigned short u) {
    _Float16 h;
    __builtin_memcpy(&h, &u, 2);
    return (float)h;
}

// ---------------------------------------------------------------------------
// K1: x->bf16 conv + per-chunk bin histogram (chunk-major coalesced stores)
//     + bin16 cache. 1024 threads: 16 waves/CU to hide gather latency.
// ---------------------------------------------------------------------------
__global__ __launch_bounds__(HTHR) void prep_kernel(
    const int* __restrict__ edge_index,   // [2E]
    const int* __restrict__ batch,        // [N] sorted
    const float* __restrict__ x,          // [N*DF]
    int E, int N, int echunk, unsigned int M,
    unsigned short* __restrict__ hist,    // [NCHUNK*NBINS] chunk-major
    unsigned short* __restrict__ bin16,   // [E]
    unsigned short* __restrict__ xb)      // [N*DF] bf16
{
    const int blk = blockIdx.x, t = threadIdx.x;

    const int nf4 = N * DF / 4;
    for (int i = blk * HTHR + t; i < nf4; i += NCHUNK * HTHR) {
        const float4 v = ((const float4*)x)[i];
        ushort4 o;
        o.x = f2bf(v.x); o.y = f2bf(v.y); o.z = f2bf(v.z); o.w = f2bf(v.w);
        ((ushort4*)xb)[i] = o;
    }

    __shared__ int lh[NBINS];             // 16 KB
    for (int i = t; i < NBINS; i += HTHR) lh[i] = 0;
    __syncthreads();
    const int* __restrict__ src = edge_index;
    const int* __restrict__ dst = edge_index + E;
    const int lo = blk * echunk;
    const int hi = min(E, lo + echunk);
    for (int e = lo + t; e < hi; e += HTHR) {
        const int g = batch[dst[e]];
        const int r = (int)__umulhi((unsigned int)src[e], M);
        const int b = (g << 3) | r;
        bin16[e] = (unsigned short)b;
        atomicAdd(&lh[b], 1);
    }
    __syncthreads();
    for (int i = t; i < NBINS; i += HTHR)        // coalesced u16 row write
        hist[(size_t)blk * NBINS + i] = (unsigned short)lh[i];
}

// ---------------------------------------------------------------------------
// K2: per-bin prefix over chunks with chunk-major layout. Block g owns bins
//     8g..8g+7; thread t holds the 8 bins' counts at chunk t (one uint4).
// ---------------------------------------------------------------------------
__global__ __launch_bounds__(NTHR) void scan_kernel(
    const unsigned short* __restrict__ hist,   // [NCHUNK*NBINS]
    unsigned short* __restrict__ baseT,        // [NCHUNK*NBINS]
    unsigned int* __restrict__ binpre,         // [NBINS]
    unsigned int* __restrict__ blocksum)       // [NGRAPH]
{
    __shared__ int wt[4];
    __shared__ int btot[8];
    const int g = blockIdx.x, t = threadIdx.x;
    const int lane = t & 63, wv = t >> 6;

    const uint4 raw = *(const uint4*)(hist + (size_t)t * NBINS + 8 * g);
    int v[8];
    v[0] = raw.x & 0xffff; v[1] = raw.x >> 16;
    v[2] = raw.y & 0xffff; v[3] = raw.y >> 16;
    v[4] = raw.z & 0xffff; v[5] = raw.z >> 16;
    v[6] = raw.w & 0xffff; v[7] = raw.w >> 16;

    int pre[8];
#pragma unroll
    for (int k = 0; k < 8; ++k) {
        int p = v[k];
#pragma unroll
        for (int d = 1; d < 64; d <<= 1) {
            const int u = __shfl_up(p, d, 64);
            if (lane >= d) p += u;
        }
        if (lane == 63) wt[wv] = p;
        __syncthreads();
        int add = 0;
#pragma unroll
        for (int i = 0; i < 4; ++i) if (i < wv) add += wt[i];
        pre[k] = p + add - v[k];
        if (t == NTHR - 1) btot[k] = p + add;
        __syncthreads();
    }

    uint4 o;
    o.x = (unsigned int)(pre[0] & 0xffff) | ((unsigned int)(pre[1] & 0xffff) << 16);
    o.y = (unsigned int)(pre[2] & 0xffff) | ((unsigned int)(pre[3] & 0xffff) << 16);
    o.z = (unsigned int)(pre[4] & 0xffff) | ((unsigned int)(pre[5] & 0xffff) << 16);
    o.w = (unsigned int)(pre[6] & 0xffff) | ((unsigned int)(pre[7] & 0xffff) << 16);
    *(uint4*)(baseT + (size_t)t * NBINS + 8 * g) = o;

    if (t < 8) {
        int e = 0;
#pragma unroll
        for (int j = 0; j < 8; ++j) if (j < t) e += btot[j];
        binpre[(g << 3) | t] = (unsigned int)e;
        if (t == 7) blocksum[g] = (unsigned int)(e + btot[7]);
    }
}

// ---------------------------------------------------------------------------
// K3: scatter into bin-contiguous order. 1024 threads (16 waves/CU).
//     Preamble (threads 0-255): 512-wide scan of blocksum. Block 0 -> soff[].
// ---------------------------------------------------------------------------
__global__ __launch_bounds__(HTHR) void scatter_kernel(
    const int* __restrict__ edge_index,
    const float* __restrict__ edge_attr,
    const unsigned short* __restrict__ bin16,
    const unsigned short* __restrict__ baseT,
    const unsigned int* __restrict__ binpre,
    const unsigned int* __restrict__ blocksum,
    int E, int echunk,
    int* __restrict__ soff,               // [NBINS+1] (written by block 0)
    unsigned int* __restrict__ ed)        // [E]: lo16 src, hi16 fp16(w)
{
    __shared__ int s512[NGRAPH];
    __shared__ int lcur[NBINS];
    __shared__ int wt[4];
    const int blk = blockIdx.x, t = threadIdx.x;
    const int lane = t & 63, wv = t >> 6;

    {   // exclusive scan of 512 per-g totals (threads 0-255 meaningful)
        const int2 v = (t < 256) ? ((const int2*)blocksum)[t] : make_int2(0, 0);
        const int s = v.x + v.y;
        int p = s;
#pragma unroll
        for (int d = 1; d < 64; d <<= 1) {
            const int u = __shfl_up(p, d, 64);
            if (lane >= d) p += u;
        }
        if (lane == 63 && wv < 4) wt[wv] = p;
        __syncthreads();
        if (t < 256) {
            int add = 0;
#pragma unroll
            for (int i = 0; i < 4; ++i) if (i < wv) add += wt[i];
            const int excl = p + add - s;
            s512[2 * t]     = excl;
            s512[2 * t + 1] = excl + v.x;
        }
    }
    __syncthreads();
    for (int i = t; i < NBINS; i += HTHR) {
        const int sv = s512[i >> 3] + (int)binpre[i];
        if (blk == 0) soff[i] = sv;
        lcur[i] = sv + (int)baseT[(size_t)blk * NBINS + i];   // coalesced
    }
    if (blk == 0 && t == 0) soff[NBINS] = E;
    __syncthreads();

    const int lo = blk * echunk;
    const int hi = min(E, lo + echunk);
    for (int e = lo + t; e < hi; e += HTHR) {
        const int b = bin16[e];
        const int p = atomicAdd(&lcur[b], 1);
        ed[p] = (unsigned int)(edge_index[e] & 0xffff)
              | ((unsigned int)f2h(edge_attr[e]) << 16);
    }
}

// ---------------------------------------------------------------------------
// K4: per-bin gather + accumulate -> partial[bin][96]. blockIdx=bin=g*8+r:
//     consecutive blocks round-robin XCDs -> slice r's xb (1.2 MB) stays
//     XCD-L2-local. NO fences.
// ---------------------------------------------------------------------------
__global__ __launch_bounds__(NTHR) void aggregate_kernel(
    const unsigned int* __restrict__ ed,
    const int* __restrict__ soff,
    const unsigned short* __restrict__ xb,
    float* __restrict__ partial)          // [NBINS*DF]
{
    __shared__ float sh4[4][DF];
    const int bin = blockIdx.x, t = threadIdx.x;
    const int lane = t & 63, wv = t >> 6;
    const int start = soff[bin];
    const int end   = soff[bin + 1];
    const int eg = lane >> 3;
    const int fc = lane & 7;

    float acc[12];
#pragma unroll
    for (int i = 0; i < 12; ++i) acc[i] = 0.f;

    int e = start + wv * 8 + eg;
    unsigned int sw = (e < end) ? ed[e] : 0u;
    while (e < end) {
        const int en = e + 32;
        const unsigned int swn = (en < end) ? ed[en] : 0u;
        const float w = h2f((unsigned short)(sw >> 16));
        const ushort4* __restrict__ row =
            (const ushort4*)xb + (size_t)(sw & 0xffffu) * 24;
#pragma unroll
        for (int c = 0; c < 3; ++c) {
            const ushort4 vv = row[fc + c * 8];
            acc[c * 4 + 0] += w * bf2f(vv.x);
            acc[c * 4 + 1] += w * bf2f(vv.y);
            acc[c * 4 + 2] += w * bf2f(vv.z);
            acc[c * 4 + 3] += w * bf2f(vv.w);
        }
        e = en; sw = swn;
    }
#pragma unroll
    for (int m = 8; m <= 32; m <<= 1) {
#pragma unroll
        for (int i = 0; i < 12; ++i) acc[i] += __shfl_xor(acc[i], m, 64);
    }
    if (eg == 0) {
#pragma unroll
        for (int c = 0; c < 3; ++c)
#pragma unroll
            for (int k = 0; k < 4; ++k)
                sh4[wv][c * 32 + fc * 4 + k] = acc[c * 4 + k];
    }
    __syncthreads();
    if (t < DF)
        partial[(size_t)bin * DF + t] =
            sh4[0][t] + sh4[1][t] + sh4[2][t] + sh4[3][t];
}

// ---------------------------------------------------------------------------
// K5: reduce 8 range-partials + mean (bsearch counts) + MLP head.
// ---------------------------------------------------------------------------
__global__ __launch_bounds__(128) void finish_kernel(
    const float* __restrict__ partial,    // [NBINS*DF]
    const int* __restrict__ batch,        // [N] sorted
    int N,
    const float* __restrict__ W1,
    const float* __restrict__ b1,
    const float* __restrict__ W2,
    const float* __restrict__ b2,
    float* __restrict__ out)
{
    __shared__ float sW1[DF * DHID];
    __shared__ float fin[DF];
    __shared__ int   scnt[2];
    const int g = blockIdx.x, t = threadIdx.x;

    if (t < 2) {
        const int key = g + t;
        int lo = 0, hi = N;
        while (lo < hi) {
            const int m = (lo + hi) >> 1;
            if (batch[m] < key) lo = m + 1; else hi = m;
        }
        scnt[t] = lo;
    }
    for (int i = t; i < DF * DHID; i += 128) sW1[i] = W1[i];
    __syncthreads();

    if (t < DF) {
        float s = 0.f;
#pragma unroll
        for (int r = 0; r < 8; ++r)
            s += partial[(size_t)((g << 3) | r) * DF + t];
        const int cnt = scnt[1] - scnt[0];
        fin[t] = fmaxf(s / fmaxf((float)cnt, 1.f), 0.f);
    }
    __syncthreads();
    if (t < 16) {
        float v = 0.f;
        if (t < DHID) {
            float h = b1[t];
            for (int f = 0; f < DF; ++f) h += fin[f] * sW1[f * DHID + t];
            v = fmaxf(h, 0.f) * W2[t];
        }
#pragma unroll
        for (int m = 1; m < 16; m <<= 1) v += __shfl_xor(v, m, 16);
        if (t == 0) out[g] = v + b2[0];
    }
}

// ---------------------------------------------------------------------------
extern "C" void kernel_launch(void* const* d_in, const int* in_sizes, int n_in,
                              void* d_out, int out_size, void* d_ws, size_t ws_size,
                              hipStream_t stream) {
    const float* x          = (const float*)d_in[0];
    const int*   edge_index = (const int*)  d_in[1];
    const float* edge_attr  = (const float*)d_in[2];
    const int*   batch      = (const int*)  d_in[3];
    const float* W1         = (const float*)d_in[4];
    const float* b1         = (const float*)d_in[5];
    const float* W2         = (const float*)d_in[6];
    const float* b2         = (const float*)d_in[7];

    const int E = in_sizes[1] / 2;   // 800000
    const int N = in_sizes[3];       // 50000 (< 65536: src fits u16)
    const int echunk = (E + NCHUNK - 1) / NCHUNK;
    const unsigned int RDIV = (unsigned int)((N + 7) / 8);
    const unsigned int M = (unsigned int)((0x100000000ULL + RDIV - 1) / RDIV);

    char* ws = (char*)d_ws;
    unsigned int*   ed    = (unsigned int*)ws;                       // 4E
    unsigned short* bin16 = (unsigned short*)(ws + (size_t)4 * E);   // 2E
    unsigned short* xb    = (unsigned short*)(ws + (size_t)6 * E);   // 2*N*DF
    char* tail = ws + (size_t)6 * E + (size_t)2 * N * DF;
    tail = (char*)(((size_t)tail + 255) & ~(size_t)255);
    unsigned short* hist     = (unsigned short*)tail;                  // 2 MB
    unsigned short* baseT    = hist + (size_t)NCHUNK * NBINS;          // 2 MB
    unsigned int*   binpre   = (unsigned int*)(baseT + (size_t)NCHUNK * NBINS);
    unsigned int*   blocksum = binpre + NBINS;
    int*            soff     = (int*)(blocksum + NGRAPH);              // NBINS+1
    float*          partial  = (float*)(soff + NBINS + 4);             // NBINS*DF

    prep_kernel<<<NCHUNK, HTHR, 0, stream>>>(edge_index, batch, x, E, N,
                                             echunk, M, hist, bin16, xb);
    scan_kernel<<<NGRAPH, NTHR, 0, stream>>>(hist, baseT, binpre, blocksum);
    scatter_kernel<<<NCHUNK, HTHR, 0, stream>>>(edge_index, edge_attr, bin16,
                                                baseT, binpre, blocksum,
                                                E, echunk, soff, ed);
    aggregate_kernel<<<NBINS, NTHR, 0, stream>>>(ed, soff, xb, partial);
    finish_kernel<<<NGRAPH, 128, 0, stream>>>(partial, batch, N,
                                              W1, b1, W2, b2, (float*)d_out);
}

// Round 14
// 56.263 us; speedup vs baseline: 7.9894x; 1.0725x over previous
//
#include <hip/hip_runtime.h>

#define NGRAPH 512
#define DF     96
#define DHID   10
#define NCHUNK 256      // sort blocks; echunk = 3125 for E=800000
#define NBINS  4096     // (graph, src-range) bins: g*8 + r
#define ECHMAX 3200     // LDS staging capacity per chunk (>= echunk)
#define HTHR   1024
#define NTHR   256

// bf16 round-to-nearest-even
static __device__ __forceinline__ unsigned short f2bf(float f) {
    unsigned int u = __float_as_uint(f);
    u = (u + 0x7fffu + ((u >> 16) & 1u)) >> 16;
    return (unsigned short)u;
}
static __device__ __forceinline__ float bf2f(unsigned short s) {
    return __uint_as_float(((unsigned int)s) << 16);
}
static __device__ __forceinline__ unsigned short f2h(float f) {
    _Float16 h = (_Float16)f;
    unsigned short u;
    __builtin_memcpy(&u, &h, 2);
    return u;
}
static __device__ __forceinline__ float h2f(unsigned short u) {
    _Float16 h;
    __builtin_memcpy(&h, &u, 2);
    return (float)h;
}

// ---------------------------------------------------------------------------
// K1 (SORT): x->bf16 conv + per-chunk bin + IN-BLOCK counting sort.
// ed layout is CHUNK-LOCAL: ed[blk*echunk + local_sorted_pos]. All stores land
// in the block's private slab -> no cross-XCD line sharing. Only exported
// metadata: localpre[blk][bin] (u16, coalesced) = in-chunk bin prefix.
// ---------------------------------------------------------------------------
__global__ __launch_bounds__(HTHR) void sort_kernel(
    const int* __restrict__ edge_index,   // [2E]
    const float* __restrict__ edge_attr,  // [E]
    const int* __restrict__ batch,        // [N] sorted
    const float* __restrict__ x,          // [N*DF]
    int E, int N, int echunk, unsigned int M,
    unsigned short* __restrict__ localpre, // [NCHUNK*NBINS]
    unsigned short* __restrict__ xb,       // [N*DF] bf16
    unsigned int* __restrict__ ed)         // [E] lo16 src | hi16 fp16(w)
{
    __shared__ int            lh[NBINS];        // hist, then cursors (16 KB)
    __shared__ unsigned short sbin[ECHMAX];     // per-edge bin       (6.4 KB)
    __shared__ unsigned int   sval[ECHMAX];     // per-edge payload  (12.8 KB)
    __shared__ int            wvsum[16];

    const int blk = blockIdx.x, t = threadIdx.x;
    const int lane = t & 63, wv = t >> 6;

    // --- x -> bf16 (grid-strided) ---
    const int nf4 = N * DF / 4;
    for (int i = blk * HTHR + t; i < nf4; i += NCHUNK * HTHR) {
        const float4 v = ((const float4*)x)[i];
        ushort4 o;
        o.x = f2bf(v.x); o.y = f2bf(v.y); o.z = f2bf(v.z); o.w = f2bf(v.w);
        ((ushort4*)xb)[i] = o;
    }

    for (int i = t; i < NBINS; i += HTHR) lh[i] = 0;
    __syncthreads();

    // --- bin + payload + LDS hist ---
    const int* __restrict__ src = edge_index;
    const int* __restrict__ dst = edge_index + E;
    const int lo = blk * echunk;
    const int hi = min(E, lo + echunk);
    for (int e = lo + t; e < hi; e += HTHR) {
        const int g = batch[dst[e]];
        const int r = (int)__umulhi((unsigned int)src[e], M);
        const int b = (g << 3) | r;
        sbin[e - lo] = (unsigned short)b;
        sval[e - lo] = (unsigned int)(src[e] & 0xffff)
                     | ((unsigned int)f2h(edge_attr[e]) << 16);
        atomicAdd(&lh[b], 1);
    }
    __syncthreads();

    // --- block-wide exclusive scan of lh[4096], 4 bins/thread ---
    const int v0 = lh[4 * t], v1 = lh[4 * t + 1],
              v2 = lh[4 * t + 2], v3 = lh[4 * t + 3];
    const int s = v0 + v1 + v2 + v3;
    int p = s;
#pragma unroll
    for (int d = 1; d < 64; d <<= 1) {
        const int u = __shfl_up(p, d, 64);
        if (lane >= d) p += u;
    }
    if (lane == 63) wvsum[wv] = p;
    __syncthreads();
    int add = 0;
#pragma unroll
    for (int i = 0; i < 16; ++i) if (i < wv) add += wvsum[i];
    const int ex = p - s + add;                  // block-exclusive prefix

    ushort4 o;                                   // export coalesced u16x4
    o.x = (unsigned short)ex;
    o.y = (unsigned short)(ex + v0);
    o.z = (unsigned short)(ex + v0 + v1);
    o.w = (unsigned short)(ex + v0 + v1 + v2);
    ((ushort4*)(localpre + (size_t)blk * NBINS))[t] = o;
    __syncthreads();                             // all lh reads done
    lh[4 * t]     = ex;                          // reuse hist as cursors
    lh[4 * t + 1] = ex + v0;
    lh[4 * t + 2] = ex + v0 + v1;
    lh[4 * t + 3] = ex + v0 + v1 + v2;
    __syncthreads();

    // --- place into block-private slab ---
    for (int e = lo + t; e < hi; e += HTHR) {
        const int i = e - lo;
        const int ppos = atomicAdd(&lh[sbin[i]], 1);
        ed[lo + ppos] = sval[i];
    }
}

// ---------------------------------------------------------------------------
// K2 (AGGREGATE): per-bin gather via 256 chunk-segments + register accumulate.
// blockIdx=bin=g*8+r round-robins XCDs -> slice r's xb (1.2 MB) XCD-L2-local.
// ---------------------------------------------------------------------------
__global__ __launch_bounds__(NTHR) void aggregate_kernel(
    const unsigned int* __restrict__ ed,
    const unsigned short* __restrict__ localpre,  // [NCHUNK*NBINS]
    const unsigned short* __restrict__ xb,
    int E, int echunk,
    float* __restrict__ partial)          // [NBINS*DF]
{
    __shared__ int   starts[NCHUNK];
    __shared__ int   cum[NCHUNK];
    __shared__ int   wt[4];
    __shared__ int   sT;
    __shared__ float sh4[4][DF];

    const int bin = blockIdx.x, t = threadIdx.x;
    const int lane = t & 63, wv = t >> 6;

    // segment of chunk t for this bin
    const int pb = (int)localpre[(size_t)t * NBINS + bin];
    const int pe = (bin < NBINS - 1)
                 ? (int)localpre[(size_t)t * NBINS + bin + 1]
                 : (min(echunk, E - t * echunk));
    const int cnt = pe - pb;
    starts[t] = t * echunk + pb;

    int p = cnt;                                  // exclusive scan of counts
#pragma unroll
    for (int d = 1; d < 64; d <<= 1) {
        const int u = __shfl_up(p, d, 64);
        if (lane >= d) p += u;
    }
    if (lane == 63) wt[wv] = p;
    __syncthreads();
    int add = 0;
#pragma unroll
    for (int i = 0; i < 4; ++i) if (i < wv) add += wt[i];
    const int incl = p + add;
    cum[t] = incl - cnt;
    if (t == NTHR - 1) sT = incl;
    __syncthreads();
    const int T = sT;

    const int eg = lane >> 3;                     // 8 edge-slots / wave
    const int fc = lane & 7;                      // 8B feature chunk lane
    float acc[12];
#pragma unroll
    for (int i = 0; i < 12; ++i) acc[i] = 0.f;

    for (int k = wv * 8 + eg; k < T; k += 32) {
        // locate chunk: largest c with cum[c] <= k (uniform across fc lanes)
        int lo2 = 0, hi2 = NCHUNK - 1;
#pragma unroll
        for (int it = 0; it < 8; ++it) {
            const int m = (lo2 + hi2 + 1) >> 1;
            if (cum[m] <= k) lo2 = m; else hi2 = m - 1;
        }
        const unsigned int sw = ed[starts[lo2] + (k - cum[lo2])];
        const float w = h2f((unsigned short)(sw >> 16));
        const ushort4* __restrict__ row =
            (const ushort4*)xb + (size_t)(sw & 0xffffu) * 24;
#pragma unroll
        for (int c = 0; c < 3; ++c) {
            const ushort4 vv = row[fc + c * 8];
            acc[c * 4 + 0] += w * bf2f(vv.x);
            acc[c * 4 + 1] += w * bf2f(vv.y);
            acc[c * 4 + 2] += w * bf2f(vv.z);
            acc[c * 4 + 3] += w * bf2f(vv.w);
        }
    }

#pragma unroll
    for (int m = 8; m <= 32; m <<= 1) {
#pragma unroll
        for (int i = 0; i < 12; ++i) acc[i] += __shfl_xor(acc[i], m, 64);
    }
    if (eg == 0) {
#pragma unroll
        for (int c = 0; c < 3; ++c)
#pragma unroll
            for (int k2 = 0; k2 < 4; ++k2)
                sh4[wv][c * 32 + fc * 4 + k2] = acc[c * 4 + k2];
    }
    __syncthreads();
    if (t < DF)
        partial[(size_t)bin * DF + t] =
            sh4[0][t] + sh4[1][t] + sh4[2][t] + sh4[3][t];
}

// ---------------------------------------------------------------------------
// K3 (FINISH): reduce 8 range-partials + mean (bsearch counts) + MLP head.
// ---------------------------------------------------------------------------
__global__ __launch_bounds__(128) void finish_kernel(
    const float* __restrict__ partial,    // [NBINS*DF]
    const int* __restrict__ batch,        // [N] sorted
    int N,
    const float* __restrict__ W1,
    const float* __restrict__ b1,
    const float* __restrict__ W2,
    const float* __restrict__ b2,
    float* __restrict__ out)
{
    __shared__ float sW1[DF * DHID];
    __shared__ float fin[DF];
    __shared__ int   scnt[2];
    const int g = blockIdx.x, t = threadIdx.x;

    if (t < 2) {
        const int key = g + t;
        int lo = 0, hi = N;
        while (lo < hi) {
            const int m = (lo + hi) >> 1;
            if (batch[m] < key) lo = m + 1; else hi = m;
        }
        scnt[t] = lo;
    }
    for (int i = t; i < DF * DHID; i += 128) sW1[i] = W1[i];
    __syncthreads();

    if (t < DF) {
        float s = 0.f;
#pragma unroll
        for (int r = 0; r < 8; ++r)
            s += partial[(size_t)((g << 3) | r) * DF + t];
        const int cnt = scnt[1] - scnt[0];
        fin[t] = fmaxf(s / fmaxf((float)cnt, 1.f), 0.f);
    }
    __syncthreads();
    if (t < 16) {
        float v = 0.f;
        if (t < DHID) {
            float h = b1[t];
            for (int f = 0; f < DF; ++f) h += fin[f] * sW1[f * DHID + t];
            v = fmaxf(h, 0.f) * W2[t];
        }
#pragma unroll
        for (int m = 1; m < 16; m <<= 1) v += __shfl_xor(v, m, 16);
        if (t == 0) out[g] = v + b2[0];
    }
}

// ---------------------------------------------------------------------------
extern "C" void kernel_launch(void* const* d_in, const int* in_sizes, int n_in,
                              void* d_out, int out_size, void* d_ws, size_t ws_size,
                              hipStream_t stream) {
    const float* x          = (const float*)d_in[0];
    const int*   edge_index = (const int*)  d_in[1];
    const float* edge_attr  = (const float*)d_in[2];
    const int*   batch      = (const int*)  d_in[3];
    const float* W1         = (const float*)d_in[4];
    const float* b1         = (const float*)d_in[5];
    const float* W2         = (const float*)d_in[6];
    const float* b2         = (const float*)d_in[7];

    const int E = in_sizes[1] / 2;   // 800000
    const int N = in_sizes[3];       // 50000 (< 65536: src fits u16)
    const int echunk = (E + NCHUNK - 1) / NCHUNK;   // 3125 (<= ECHMAX)
    const unsigned int RDIV = (unsigned int)((N + 7) / 8);
    const unsigned int M = (unsigned int)((0x100000000ULL + RDIV - 1) / RDIV);

    // workspace: ed 4E | xb 2*N*DF | localpre 2MB | partial 1.5MB
    char* ws = (char*)d_ws;
    unsigned int*   ed = (unsigned int*)ws;                          // 4E
    unsigned short* xb = (unsigned short*)(ws + (size_t)4 * E);      // 2*N*DF
    char* tail = ws + (size_t)4 * E + (size_t)2 * N * DF;
    tail = (char*)(((size_t)tail + 255) & ~(size_t)255);
    unsigned short* localpre = (unsigned short*)tail;                // 2 MB
    float*          partial  = (float*)(localpre + (size_t)NCHUNK * NBINS);

    sort_kernel<<<NCHUNK, HTHR, 0, stream>>>(edge_index, edge_attr, batch, x,
                                             E, N, echunk, M,
                                             localpre, xb, ed);
    aggregate_kernel<<<NBINS, NTHR, 0, stream>>>(ed, localpre, xb,
                                                 E, echunk, partial);
    finish_kernel<<<NGRAPH, 128, 0, stream>>>(partial, batch, N,
                                              W1, b1, W2, b2, (float*)d_out);
}